// Round 16
// baseline (1012.768 us; speedup 1.0000x reference)
//
#include <hip/hip_runtime.h>
#include <hip/hip_bf16.h>
#include <cfloat>

using bf16 = __hip_bfloat16;

typedef short short8 __attribute__((ext_vector_type(8)));
typedef float floatx16 __attribute__((ext_vector_type(16)));
union Frag { short8 v; uint2 u2[2]; };
union FragQ { short8 v; uint4 q; uint2 u2[2]; };
union U4b { uint4 q; unsigned short s[8]; };

constexpr int Bb = 8, Nn = 4096, Kk = 20;
constexpr int BN = Bb * Nn;                     // 32768
constexpr int Mrows = BN * Kk;                  // 655360
constexpr float EPSf = 1e-5f;

static __device__ __forceinline__ float b2f(bf16 v){ return __bfloat162float(v); }
static __device__ __forceinline__ bf16 f2b(float v){ return __float2bfloat16(v); }
static __device__ __forceinline__ unsigned short f2bu(float v){
  union { bf16 b; unsigned short u; } cv; cv.b = __float2bfloat16(v); return cv.u;
}
static __device__ __forceinline__ float bits2f(unsigned short u){
  union { unsigned int i; float f; } c; c.i = ((unsigned)u)<<16; return c.f;
}

// ---------------- zero workspace region ----------------
__global__ void zero_kernel(float* __restrict__ p, int n){
  int i = blockIdx.x*256 + threadIdx.x;
  if (i < n) p[i] = 0.f;
}

// ---------------- W2^T bf16 pack ----------------
__global__ void w2t_kernel(const float* __restrict__ W2f, bf16* __restrict__ W2T){
  int id = blockIdx.x*256 + threadIdx.x;   // 64*64 = 4096 elems
  if (id >= 64*64) return;
  int n = id >> 6, k = id & 63;
  W2T[id] = f2b(W2f[(size_t)k*64 + n]);
}

// ---------------- W3^T bf16 pack ----------------
__global__ void w3t_kernel(const float* __restrict__ W3f, bf16* __restrict__ W3T){
  int id = blockIdx.x*256 + threadIdx.x;   // 128*64 = 8192 elems
  if (id >= 128*64) return;
  int n = id >> 6, k = id & 63;
  W3T[id] = f2b(W3f[(size_t)k*128 + n]);
}

// ---------------- W4^T bf16 pack ----------------
__global__ void w4t_kernel(const float* __restrict__ W4f, bf16* __restrict__ W4T){
  int id = blockIdx.x*256 + threadIdx.x;   // 128*256 = 32768 elems
  if (id >= 128*256) return;
  int k = id >> 8, c = id & 255;           // coalesced read of W4f
  W4T[(size_t)c*128 + k] = f2b(W4f[id]);
}

// ---------------- W5^T bf16 pack ----------------
__global__ void w5t_kernel(const float* __restrict__ W5f, bf16* __restrict__ W5T){
  int id = blockIdx.x*256 + threadIdx.x;   // 512*512 = 262144 elems
  if (id >= 512*512) return;
  int k = id >> 9, c = id & 511;           // coalesced read of W5f
  W5T[(size_t)c*512 + k] = f2b(W5f[id]);
}

// ---------------- KNN phase A v9 (142us, issue-bound) ----------------
__global__ __launch_bounds__(256) void knnA_kernel(const float* __restrict__ x,
                                                   float* __restrict__ pv, int* __restrict__ pi){
#pragma clang fp contract(off)
  __shared__ float4 p4[512];
  __shared__ unsigned short lst[256*62];
  int blk = blockIdx.x;
  int stripe = blk & 7;
  int chunk  = (blk >> 3) & 15;
  int b      = blk >> 7;
  const float* xb = x + b*3*Nn;
  int j0 = stripe*512;
  for (int u = threadIdx.x; u < 512; u += 256){
    int j = j0 + u;
    float a0 = xb[j];
    float a1 = xb[Nn + j];
    float a2 = xb[2*Nn + j];
    float s = a0*a0; s = s + a1*a1; s = s + a2*a2;
    p4[u] = make_float4(a0, a1, a2, s);
  }
  __syncthreads();
  int i = chunk*256 + threadIdx.x;
  float xi = xb[i], yi = xb[Nn+i], zi = xb[2*Nn+i];
  float ni = xi*xi; ni = ni + yi*yi; ni = ni + zi*zi;
  float mni = -ni;
  float xi2 = xi + xi, yi2 = yi + yi, zi2 = zi + zi;
  float bv[13];
  #pragma unroll
  for (int s=0;s<13;++s) bv[s] = FLT_MAX;
  for (int g=0; g<32; ++g){
    float gm = -FLT_MAX;
    #pragma unroll
    for (int e=0;e<16;++e){
      float4 p = p4[g*16+e];
      float base = mni - p.w;
      float nd = fmaf(xi2, p.x, fmaf(yi2, p.y, fmaf(zi2, p.z, base)));
      gm = fmaxf(gm, nd);
    }
    #pragma unroll
    for (int s=12; s>=1; --s)
      bv[s] = fminf(bv[s], fmaxf(bv[s-1], gm));
    bv[0] = fminf(bv[0], gm);
  }
  float thr = bv[12];
  thr = thr - (fabsf(thr)*1e-5f + 1e-6f);
  unsigned short* ml = &lst[threadIdx.x*62];
  int cnt = 0;
  for (int u=0; u<512; ++u){
    float4 p = p4[u];
    float base = mni - p.w;
    float nd = fmaf(xi2, p.x, fmaf(yi2, p.y, fmaf(zi2, p.z, base)));
    if (nd >= thr && cnt < 60){ ml[cnt] = (unsigned short)u; ++cnt; }
  }
  float av[Kk]; int ai[Kk];
  #pragma unroll
  for (int s=0;s<Kk;++s){ av[s] = -FLT_MAX; ai[s] = 0; }
  if (cnt >= 60){
    for (int u=0; u<512; ++u){
      float4 p = p4[u];
      float dot = xi*p.x; dot = dot + yi*p.y; dot = dot + zi*p.z;
      float inner = -2.0f*dot;
      float nd = mni - inner; nd = nd - p.w;
      if (nd > av[Kk-1]){
        #pragma unroll
        for (int s=Kk-1; s>=1; --s){
          bool cs = nd > av[s];
          bool cp = nd > av[s-1];
          av[s] = cs ? (cp ? av[s-1] : nd) : av[s];
          ai[s] = cs ? (cp ? ai[s-1] : (j0+u)) : ai[s];
        }
        if (nd > av[0]){ av[0] = nd; ai[0] = j0+u; }
      }
    }
  } else {
    for (int t=0; t<cnt; ++t){
      int lj = ml[t];
      float4 p = p4[lj];
      float dot = xi*p.x; dot = dot + yi*p.y; dot = dot + zi*p.z;
      float inner = -2.0f*dot;
      float nd = mni - inner; nd = nd - p.w;
      if (nd > av[Kk-1]){
        #pragma unroll
        for (int s=Kk-1; s>=1; --s){
          bool cs = nd > av[s];
          bool cp = nd > av[s-1];
          av[s] = cs ? (cp ? av[s-1] : nd) : av[s];
          ai[s] = cs ? (cp ? ai[s-1] : (j0+lj)) : ai[s];
        }
        if (nd > av[0]){ av[0] = nd; ai[0] = j0+lj; }
      }
    }
  }
  long long base = ((long long)(b*Nn + i)*8 + stripe)*Kk;
  #pragma unroll
  for (int s=0;s<Kk;++s){ pv[base+s] = av[s]; pi[base+s] = ai[s]; }
}

// ---------------- KNN phase B + fused layer-1 stats ----------------
__global__ __launch_bounds__(256) void knnB_kernel(const float* __restrict__ pv,
                                                   const int* __restrict__ pi,
                                                   const float* __restrict__ x,
                                                   int* __restrict__ idx,
                                                   float* __restrict__ part){
  int p = blockIdx.x*256 + threadIdx.x;    // grid 128 x 256 = BN exactly
  long long base = (long long)p*8*Kk;
  float av[Kk]; int ai[Kk];
  #pragma unroll
  for (int s=0;s<Kk;++s){ av[s]=pv[base+s]; ai[s]=pi[base+s]; }
  for (int t=Kk; t<8*Kk; ++t){
    float nd = pv[base+t]; int j = pi[base+t];
    if (nd > av[Kk-1]){
      #pragma unroll
      for (int s=Kk-1;s>=1;--s){
        bool cs = nd > av[s];
        bool cp = nd > av[s-1];
        av[s] = cs ? (cp?av[s-1]:nd) : av[s];
        ai[s] = cs ? (cp?ai[s-1]:j) : ai[s];
      }
      if (nd > av[0]){ av[0]=nd; ai[0]=j; }
    }
  }
  #pragma unroll
  for (int s=0;s<Kk;++s) idx[(long long)p*Kk+s] = ai[s];
  int b = p >> 12, n = p & 4095;
  const float* xb = x + b*3*Nn;
  float cx = xb[n], cy = xb[Nn+n], cz = xb[2*Nn+n];
  float snx=0.f, sny=0.f, snz=0.f;
  float a00=0.f,a01=0.f,a02=0.f,a11=0.f,a12=0.f,a22=0.f;
  #pragma unroll
  for (int s=0;s<Kk;++s){
    int j = ai[s];
    float nx = xb[j], ny = xb[Nn+j], nz = xb[2*Nn+j];
    snx += nx; sny += ny; snz += nz;
    a00 = fmaf(nx,nx,a00); a01 = fmaf(nx,ny,a01); a02 = fmaf(nx,nz,a02);
    a11 = fmaf(ny,ny,a11); a12 = fmaf(ny,nz,a12); a22 = fmaf(nz,nz,a22);
  }
  float acc[36];
  acc[0]=a00;  acc[1]=a01;  acc[2]=a02;
  acc[6]=a01;  acc[7]=a11;  acc[8]=a12;
  acc[12]=a02; acc[13]=a12; acc[14]=a22;
  acc[3]=snx*cx;  acc[4]=snx*cy;  acc[5]=snx*cz;
  acc[9]=sny*cx;  acc[10]=sny*cy; acc[11]=sny*cz;
  acc[15]=snz*cx; acc[16]=snz*cy; acc[17]=snz*cz;
  acc[18]=cx*snx; acc[19]=cx*sny; acc[20]=cx*snz;
  acc[24]=cy*snx; acc[25]=cy*sny; acc[26]=cy*snz;
  acc[30]=cz*snx; acc[31]=cz*sny; acc[32]=cz*snz;
  float k20 = (float)Kk;
  acc[21]=k20*cx*cx; acc[22]=k20*cx*cy; acc[23]=k20*cx*cz;
  acc[27]=k20*cy*cx; acc[28]=k20*cy*cy; acc[29]=k20*cy*cz;
  acc[33]=k20*cz*cx; acc[34]=k20*cz*cy; acc[35]=k20*cz*cz;
  float s6[6] = { snx, sny, snz, k20*cx, k20*cy, k20*cz };
  __shared__ float red[256];
  #pragma unroll
  for (int v=0; v<42; ++v){
    red[threadIdx.x] = (v<36)? acc[v] : s6[v-36];
    __syncthreads();
    for (int s=128; s>0; s>>=1){
      if (threadIdx.x < s) red[threadIdx.x] += red[threadIdx.x+s];
      __syncthreads();
    }
    if (threadIdx.x==0) part[blockIdx.x*48 + v] = red[0];
    __syncthreads();
  }
}

__global__ void reducef_kernel(const float* __restrict__ part, float* __restrict__ Gf,
                               float* __restrict__ sumf){
  int t = threadIdx.x;
  if (t < 42){
    float s = 0.f;
    for (int i=0;i<128;++i) s += part[i*48 + t];
    if (t<36) Gf[t]=s; else sumf[t-36]=s;
  }
}

// ---------------- G3 gram (CIN=64) with fused column sums ----------------
__global__ __launch_bounds__(256) void gram3_kernel(const bf16* __restrict__ H, int M,
                                                    float* __restrict__ G,
                                                    float* __restrict__ sumh){
  __shared__ short HTa[64*68];
  __shared__ float csum[64];
  int tid = threadIdx.x, lane = tid & 63, w = tid >> 6;
  if (tid < 64) csum[tid] = 0.f;
  int nchunks = gridDim.x;
  int rpc = M / nchunks;
  int r0 = blockIdx.x*rpc;
  int mt = w >> 1, nt = w & 1;
  floatx16 acc;
  #pragma unroll
  for (int q=0;q<16;++q) acc[q]=0.f;
  int arow = (mt*32 + (lane&31))*68;
  int brow = (nt*32 + (lane&31))*68;
  int ko = (lane>>5)*8;
  int c0s = (tid & 7)*8;
  float cs[8];
  #pragma unroll
  for (int j=0;j<8;++j) cs[j]=0.f;
  for (int rb=r0; rb<r0+rpc; rb+=64){
    #pragma unroll
    for (int s=0;s<2;++s){
      int e = tid + s*256;
      int row = e >> 3;
      U4b va; va.q = *(const uint4*)&H[(size_t)(rb+row)*64 + c0s];
      #pragma unroll
      for (int j=0;j<8;++j){
        HTa[(c0s+j)*68 + row] = (short)va.s[j];
        cs[j] += bits2f(va.s[j]);
      }
    }
    __syncthreads();
    #pragma unroll
    for (int kc=0;kc<64;kc+=16){
      Frag a, b;
      const short* ap = &HTa[arow + kc + ko];
      const short* bp = &HTa[brow + kc + ko];
      a.u2[0] = *(const uint2*)ap;  a.u2[1] = *(const uint2*)(ap+4);
      b.u2[0] = *(const uint2*)bp;  b.u2[1] = *(const uint2*)(bp+4);
      acc = __builtin_amdgcn_mfma_f32_32x32x16_bf16(a.v, b.v, acc, 0, 0, 0);
    }
    __syncthreads();
  }
  int col = lane & 31, rbase = 4*(lane>>5);
  #pragma unroll
  for (int r=0;r<16;++r){
    int row = (r&3) + 8*(r>>2) + rbase;
    atomicAdd(&G[(size_t)(mt*32 + row)*64 + nt*32 + col], acc[r]);
  }
  #pragma unroll
  for (int j=0;j<8;++j) atomicAdd(&csum[c0s+j], cs[j]);
  __syncthreads();
  if (tid < 64) atomicAdd(&sumh[tid], csum[tid]);
}

// ---------------- G5 gram (CIN=512): 128-wide tiles + fused column sums ----------------
__global__ __launch_bounds__(256) void gram5_kernel(const bf16* __restrict__ H,
                                                    float* __restrict__ G,
                                                    float* __restrict__ sumh){
  __shared__ short HTa[128*68];
  __shared__ short HTb[128*68];
  __shared__ float csum[128];
  int blk = blockIdx.x;
  int pair = blk & 15;
  int chunk = blk >> 4;            // 0..31
  int tr = pair >> 2, tc = pair & 3;
  bool diag = (tr == tc);
  int tid = threadIdx.x, lane = tid & 63, w = tid >> 6;   // 4 waves
  if (tid < 128) csum[tid] = 0.f;
  int rpc = BN / 32;               // 1024
  int r0 = chunk*rpc;
  int pl = lane & 31, ko = (lane>>5)*8, rbase = 4*(lane>>5);
  int mt = w;
  int arow = (mt*32 + pl)*68;
  floatx16 acc[4];
  #pragma unroll
  for (int nt=0;nt<4;++nt)
    #pragma unroll
    for (int q=0;q<16;++q) acc[nt][q]=0.f;
  int c0s = (tid & 15)*8;
  float cs[8];
  #pragma unroll
  for (int j=0;j<8;++j) cs[j]=0.f;
  const short* Bbase = diag ? HTa : HTb;
  for (int rb=r0; rb<r0+rpc; rb+=64){
    #pragma unroll
    for (int s=0;s<4;++s){
      int e = tid + s*256;
      int row = e >> 4;
      U4b va; va.q = *(const uint4*)&H[(size_t)(rb+row)*512 + tr*128 + c0s];
      #pragma unroll
      for (int j=0;j<8;++j) HTa[(c0s+j)*68 + row] = (short)va.s[j];
      if (diag){
        #pragma unroll
        for (int j=0;j<8;++j) cs[j] += bits2f(va.s[j]);
      } else {
        U4b vb; vb.q = *(const uint4*)&H[(size_t)(rb+row)*512 + tc*128 + c0s];
        #pragma unroll
        for (int j=0;j<8;++j) HTb[(c0s+j)*68 + row] = (short)vb.s[j];
      }
    }
    __syncthreads();
    #pragma unroll
    for (int kc=0;kc<64;kc+=16){
      Frag a;
      const short* ap = &HTa[arow + kc + ko];
      a.u2[0] = *(const uint2*)ap;  a.u2[1] = *(const uint2*)(ap+4);
      #pragma unroll
      for (int nt=0;nt<4;++nt){
        Frag b;
        const short* bp = &Bbase[(nt*32 + pl)*68 + kc + ko];
        b.u2[0] = *(const uint2*)bp;  b.u2[1] = *(const uint2*)(bp+4);
        acc[nt] = __builtin_amdgcn_mfma_f32_32x32x16_bf16(a.v, b.v, acc[nt], 0, 0, 0);
      }
    }
    __syncthreads();
  }
  #pragma unroll
  for (int nt=0;nt<4;++nt){
    #pragma unroll
    for (int r=0;r<16;++r){
      int row = (r&3) + 8*(r>>2) + rbase;
      atomicAdd(&G[(size_t)(tr*128 + mt*32 + row)*512 + tc*128 + nt*32 + pl], acc[nt][r]);
    }
  }
  if (diag){
    #pragma unroll
    for (int j=0;j<8;++j) atomicAdd(&csum[c0s+j], cs[j]);
    __syncthreads();
    if (tid < 128) atomicAdd(&sumh[tr*128 + tid], csum[tid]);
  }
}

// ---------------- P = G @ W (generic, small cases) ----------------
__global__ void kP_kernel(const float* __restrict__ G, const float* __restrict__ Wf,
                          float* __restrict__ P, int Cin, int Cout){
  int id = blockIdx.x*256 + threadIdx.x;
  if (id >= Cin*Cout) return;
  int i = id / Cout, j = id - i*Cout;
  float s = 0.f;
  for (int k=0;k<Cin;++k) s = fmaf(G[(size_t)i*Cin+k], Wf[(size_t)k*Cout+j], s);
  P[id] = s;
}

// ---------------- P5 = G5 @ W5 specialized (512x512x512) ----------------
__global__ __launch_bounds__(256) void kP512_kernel(const float* __restrict__ G,
                                                    const float* __restrict__ Wf,
                                                    float* __restrict__ P){
  __shared__ float Gs[8][512];   // 16 KB
  int tid = threadIdx.x;
  int r0 = (blockIdx.x >> 1) * 8;          // 64 row-groups
  int j  = (blockIdx.x & 1) * 256 + tid;   // col
  for (int u = tid; u < 8*512; u += 256)
    Gs[u >> 9][u & 511] = G[(size_t)(r0 + (u >> 9))*512 + (u & 511)];
  __syncthreads();
  float acc[8];
  #pragma unroll
  for (int i=0;i<8;++i) acc[i]=0.f;
  for (int k=0;k<512;++k){
    float wv = Wf[(size_t)k*512 + j];
    #pragma unroll
    for (int i=0;i<8;++i) acc[i] = fmaf(Gs[i][k], wv, acc[i]);
  }
  #pragma unroll
  for (int i=0;i<8;++i) P[(size_t)(r0+i)*512 + j] = acc[i];
}

// ---------------- scale/shift v2: i-parallel (16 sub-slices/column) ----------------
__global__ __launch_bounds__(256) void kFinal_kernel(const float* __restrict__ P,
                              const float* __restrict__ sumh,
                              const float* __restrict__ Wf, const float* __restrict__ g,
                              const float* __restrict__ bb, float* __restrict__ scale,
                              float* __restrict__ shift, int Cin, int Cout, float invM){
  __shared__ float redm[256], rede[256];
  int tid = threadIdx.x;
  int j = blockIdx.x*16 + (tid & 15);
  int sub = tid >> 4;
  float mean = 0.f, e2 = 0.f;
  for (int i = sub; i < Cin; i += 16){
    float w = Wf[(size_t)i*Cout + j];
    mean = fmaf(sumh[i], w, mean);
    e2   = fmaf(w, P[(size_t)i*Cout + j], e2);
  }
  redm[tid] = mean; rede[tid] = e2;
  __syncthreads();
  for (int s = 128; s >= 16; s >>= 1){
    if (tid < s){ redm[tid] += redm[tid+s]; rede[tid] += rede[tid+s]; }
    __syncthreads();
  }
  if (tid < 16){
    float m = redm[tid]*invM, e = rede[tid]*invM;
    float var = e - m*m;
    float inv = rsqrtf(var + EPSf);
    float sc = g[j]*inv;
    scale[j] = sc;
    shift[j] = bb[j] - m*sc;
  }
}

// ---------------- layer-2 stats ----------------
__global__ __launch_bounds__(512) void stats2_kernel(const float* __restrict__ x,
    const int* __restrict__ idx, const float* __restrict__ W1f,
    const float* __restrict__ sc1v, const float* __restrict__ sh1v,
    float* __restrict__ G2, float* __restrict__ sum2){
  __shared__ float W1s[6][64];
  __shared__ float fsh[64][8];
  __shared__ short H1T[64*68];
  __shared__ float csum[64];
  int tid = threadIdx.x, lane = tid & 63, w = tid >> 6;   // 8 waves
  if (tid < 384) W1s[tid>>6][tid&63] = W1f[tid];
  if (tid < 64) csum[tid] = 0.f;
  int rp = tid >> 4, cq = tid & 15, c0 = cq*4;
  float sca[4], sha[4];
  #pragma unroll
  for (int k=0;k<4;++k){ sca[k]=sc1v[c0+k]; sha[k]=sh1v[c0+k]; }
  int mt = w & 1, nt = (w>>1) & 1, kh = w >> 2;
  int arow = (mt*32 + (lane&31))*68;
  int brow = (nt*32 + (lane&31))*68;
  int ko = (lane>>5)*8;
  floatx16 acc;
  #pragma unroll
  for (int q=0;q<16;++q) acc[q]=0.f;
  float cs[4] = {0.f,0.f,0.f,0.f};
  int rpc = Mrows / gridDim.x;
  int r0 = blockIdx.x * rpc;
  __syncthreads();
  for (int rb=r0; rb<r0+rpc; rb+=64){
    {
      int r = tid>>3, e = tid&7;
      if (e < 6){
        int grow = rb + r;
        int bn = grow / Kk;
        int b = bn >> 12, n = bn & 4095;
        int j = idx[grow];
        const float* xb = x + b*3*Nn;
        fsh[r][e] = (e<3) ? xb[e*Nn + j] : xb[(e-3)*Nn + n];
      }
    }
    __syncthreads();
    {
      float y0[4]={0,0,0,0}, y1[4]={0,0,0,0};
      int ra = rp*2, rbw = rp*2+1;
      #pragma unroll
      for (int i=0;i<6;++i){
        float fa = fsh[ra][i], fb = fsh[rbw][i];
        float4 wv = *(const float4*)&W1s[i][c0];
        y0[0]=fmaf(fa,wv.x,y0[0]); y0[1]=fmaf(fa,wv.y,y0[1]);
        y0[2]=fmaf(fa,wv.z,y0[2]); y0[3]=fmaf(fa,wv.w,y0[3]);
        y1[0]=fmaf(fb,wv.x,y1[0]); y1[1]=fmaf(fb,wv.y,y1[1]);
        y1[2]=fmaf(fb,wv.z,y1[2]); y1[3]=fmaf(fb,wv.w,y1[3]);
      }
      #pragma unroll
      for (int k=0;k<4;++k){
        float va = fmaxf(fmaf(y0[k],sca[k],sha[k]),0.f);
        float vb = fmaxf(fmaf(y1[k],sca[k],sha[k]),0.f);
        cs[k] += va; cs[k] += vb;
        unsigned int pk = f2bu(va) | ((unsigned)f2bu(vb)<<16);
        *(unsigned int*)&H1T[(c0+k)*68 + ra] = pk;
      }
    }
    __syncthreads();
    {
      int kc = kh*32;
      #pragma unroll
      for (int s=0;s<2;++s){
        Frag a, b;
        const short* ap = &H1T[arow + kc + s*16 + ko];
        const short* bp = &H1T[brow + kc + s*16 + ko];
        a.u2[0] = *(const uint2*)ap;  a.u2[1] = *(const uint2*)(ap+4);
        b.u2[0] = *(const uint2*)bp;  b.u2[1] = *(const uint2*)(bp+4);
        acc = __builtin_amdgcn_mfma_f32_32x32x16_bf16(a.v, b.v, acc, 0, 0, 0);
      }
    }
    __syncthreads();
  }
  int col = lane & 31, rbase = 4*(lane>>5);
  #pragma unroll
  for (int r=0;r<16;++r){
    int row = (r&3) + 8*(r>>2) + rbase;
    atomicAdd(&G2[(size_t)(mt*32+row)*64 + nt*32+col], acc[r]);
  }
  #pragma unroll
  for (int k=0;k<4;++k) atomicAdd(&csum[c0+k], cs[k]);
  __syncthreads();
  if (tid < 64) atomicAdd(&sum2[tid], csum[tid]);
}

// ---------------- fused layers 1+2 v2: MFMA produce2 + col-owner maxpool ----------------
// Block = 320 rows = 16 points, 512 threads, 5 tiles of 64 (fl34 skeleton).
// Per tile: gather f -> produce1 (VALU, H1 bf16 row-major LDS) -> produce2 (waves 0-3:
// 4 MFMA each, H1@W2T, bn+relu, transposed-packed store; wave 4 concurrently scans H1
// for x1 maxpool - both only READ h1s) -> coalesced H2 global write + x2 scan.
// Replaces the round-0 1-wave-block VALU GEMM (5.2 GFLOP on VALU).
__global__ __launch_bounds__(512) void fl12_kernel(const float* __restrict__ x,
    const int* __restrict__ idx, const float* __restrict__ W1f,
    const float* __restrict__ sc1v, const float* __restrict__ sh1v,
    const bf16* __restrict__ W2T, const float* __restrict__ sc2v,
    const float* __restrict__ sh2v, bf16* __restrict__ H2, bf16* __restrict__ cat){
  __shared__ float W1s[6][64];             // 1.5 KB
  __shared__ float fsh[64][8];             // 2 KB
  __shared__ short h1s[64*68];             // 8.5 KB row-major bf16 H1
  __shared__ short h2sT[64*68];            // 8.5 KB transposed bf16 H2 [col][row]
  __shared__ unsigned short mx1u[16*64];   // 2 KB
  __shared__ unsigned short mx2u[16*64];   // 2 KB
  int tid = threadIdx.x, lane = tid & 63, w = tid >> 6;
  int pl = lane & 31;
  int ko = (lane >> 5)*8;
  int rbase = 4*(lane>>5);
  if (tid < 384) W1s[tid>>6][tid&63] = W1f[tid];
  {
    unsigned* p1 = (unsigned*)mx1u;
    unsigned* p2 = (unsigned*)mx2u;
    for (int u=tid; u<512; u+=512){ p1[u]=0u; p2[u]=0u; }
  }
  // produce1 mapping: 32 row-pairs x 16 col-quads
  int rp = tid >> 4, cq = tid & 15, c0 = cq*4;
  float sca1[4], sha1[4];
  #pragma unroll
  for (int k=0;k<4;++k){ sca1[k]=sc1v[c0+k]; sha1[k]=sh1v[c0+k]; }
  // produce2 mapping (waves 0-3): 2x2 C-tiles of 64x64, K=64
  int mt = (w>>1)&1, nt = w&1;
  int pcol = nt*32 + pl;
  float sca2 = sc2v[pcol], sha2 = sh2v[pcol];
  FragQ bfr[4];
  #pragma unroll
  for (int kq=0;kq<4;++kq)
    bfr[kq].q = *(const uint4*)&W2T[(size_t)pcol*64 + kq*16 + ko];
  int a2row = (mt*32 + pl)*68;
  int r0 = blockIdx.x * 320;
  int bn0 = blockIdx.x * 16;
  __syncthreads();
  for (int t=0; t<5; ++t){
    int g0 = r0 + t*64;
    // ---- gather features ----
    {
      int r = tid>>3, e = tid&7;
      if (e < 6){
        int grow = g0 + r;
        int bn = grow / Kk;
        int b = bn >> 12, n = bn & 4095;
        int j = idx[grow];
        const float* xb = x + b*3*Nn;
        fsh[r][e] = (e<3) ? xb[e*Nn + j] : xb[(e-3)*Nn + n];
      }
    }
    __syncthreads();
    // ---- produce1: H1 = relu(bn1(f @ W1)) -> bf16 row-major h1s ----
    {
      float y0[4]={0,0,0,0}, y1[4]={0,0,0,0};
      int ra = rp*2, rb = rp*2+1;
      #pragma unroll
      for (int i=0;i<6;++i){
        float fa = fsh[ra][i], fb = fsh[rb][i];
        float4 wv = *(const float4*)&W1s[i][c0];
        y0[0]=fmaf(fa,wv.x,y0[0]); y0[1]=fmaf(fa,wv.y,y0[1]);
        y0[2]=fmaf(fa,wv.z,y0[2]); y0[3]=fmaf(fa,wv.w,y0[3]);
        y1[0]=fmaf(fb,wv.x,y1[0]); y1[1]=fmaf(fb,wv.y,y1[1]);
        y1[2]=fmaf(fb,wv.z,y1[2]); y1[3]=fmaf(fb,wv.w,y1[3]);
      }
      unsigned short ua[4], ub[4];
      #pragma unroll
      for (int k=0;k<4;++k){
        ua[k] = f2bu(fmaxf(fmaf(y0[k],sca1[k],sha1[k]),0.f));
        ub[k] = f2bu(fmaxf(fmaf(y1[k],sca1[k],sha1[k]),0.f));
      }
      uint2 va; va.x = ua[0]|((unsigned)ua[1]<<16); va.y = ua[2]|((unsigned)ua[3]<<16);
      uint2 vb; vb.x = ub[0]|((unsigned)ub[1]<<16); vb.y = ub[2]|((unsigned)ub[3]<<16);
      *(uint2*)&h1s[ra*68 + c0] = va;
      *(uint2*)&h1s[rb*68 + c0] = vb;
    }
    __syncthreads();
    // ---- produce2 (waves 0-3): H2tile = relu(bn2(H1 @ W2)); wave 4: x1 scan ----
    if (w < 4){
      floatx16 pacc;
      #pragma unroll
      for (int q=0;q<16;++q) pacc[q]=0.f;
      #pragma unroll
      for (int kq=0;kq<4;++kq){
        Frag a;
        const short* ap = &h1s[a2row + kq*16 + ko];
        a.u2[0] = *(const uint2*)ap;  a.u2[1] = *(const uint2*)(ap+4);
        pacc = __builtin_amdgcn_mfma_f32_32x32x16_bf16(a.v, bfr[kq].v, pacc, 0, 0, 0);
      }
      #pragma unroll
      for (int g=0; g<4; ++g){
        unsigned short p[4];
        #pragma unroll
        for (int r=0;r<4;++r)
          p[r] = f2bu(fmaxf(fmaf(pacc[g*4+r], sca2, sha2), 0.f));
        uint2 pk; pk.x = p[0] | ((unsigned)p[1]<<16); pk.y = p[2] | ((unsigned)p[3]<<16);
        *(uint2*)&h2sT[pcol*68 + mt*32 + 8*g + rbase] = pk;
      }
    } else if (w == 4){
      int c = tid - 256;                   // 0..63
      int lr0 = t*64;
      int p = lr0/20;
      int nb = (p+1)*20 - lr0;
      unsigned ml = 0;
      for (int r=0;r<64;++r){
        unsigned v = (unsigned)(unsigned short)h1s[r*68 + c];
        ml = v > ml ? v : ml;
        if (--nb == 0){
          unsigned short* mp = &mx1u[p*64 + c];
          unsigned cur = *mp;
          if (ml > cur) *mp = (unsigned short)ml;
          ml = 0; ++p; nb = 20;
        }
      }
      if (nb != 20){
        unsigned short* mp = &mx1u[p*64 + c];
        unsigned cur = *mp;
        if (ml > cur) *mp = (unsigned short)ml;
      }
    }
    __syncthreads();
    // ---- coalesced H2 global write (all threads) + x2 scan (tid<64) ----
    {
      int row = tid >> 3, cc0 = (tid & 7)*8;
      unsigned short us[8];
      #pragma unroll
      for (int j=0;j<8;++j) us[j] = (unsigned short)h2sT[(cc0+j)*68 + row];
      uint4 v; v.x = us[0]|((unsigned)us[1]<<16); v.y = us[2]|((unsigned)us[3]<<16);
      v.z = us[4]|((unsigned)us[5]<<16); v.w = us[6]|((unsigned)us[7]<<16);
      *(uint4*)&H2[(size_t)(g0+row)*64 + cc0] = v;
    }
    if (tid < 64){
      int c = tid;
      int lr0 = t*64;
      int p = lr0/20;
      int nb = (p+1)*20 - lr0;
      unsigned ml = 0;
      for (int r=0;r<64;++r){
        unsigned v = (unsigned)(unsigned short)h2sT[c*68 + r];
        ml = v > ml ? v : ml;
        if (--nb == 0){
          unsigned short* mp = &mx2u[p*64 + c];
          unsigned cur = *mp;
          if (ml > cur) *mp = (unsigned short)ml;
          ml = 0; ++p; nb = 20;
        }
      }
      if (nb != 20){
        unsigned short* mp = &mx2u[p*64 + c];
        unsigned cur = *mp;
        if (ml > cur) *mp = (unsigned short)ml;
      }
    }
    __syncthreads();
  }
  // ---- write x1/x2 maxima to cat ----
  if (tid < 256){
    int p = tid >> 4, cc0 = (tid & 15)*4;
    uint2 v1 = *(const uint2*)&mx1u[p*64 + cc0];
    *(uint2*)&cat[(size_t)(bn0+p)*512 + cc0] = v1;
    uint2 v2 = *(const uint2*)&mx2u[p*64 + cc0];
    *(uint2*)&cat[(size_t)(bn0+p)*512 + 64 + cc0] = v2;
  }
}

// ---------------- layer-4 stats: MFMA produce + MFMA Gram ----------------
__global__ __launch_bounds__(512) void stats4_kernel(const bf16* __restrict__ H2,
    const bf16* __restrict__ W3T, const float* __restrict__ sc3v, const float* __restrict__ sh3v,
    float* __restrict__ G4, float* __restrict__ sum4){
  __shared__ short h2s[64*68];
  __shared__ short H3T[128*68];
  __shared__ float csum[128];
  int tid = threadIdx.x, lane = tid & 63, w = tid >> 6;   // 8 waves
  if (tid < 128) csum[tid] = 0.f;
  int trow = tid >> 3, tc0 = (tid & 7)*8;
  int pl  = lane & 31;
  int ko  = (lane >> 5)*8;
  int pmt = w >> 2, pnt = w & 3;
  int parow = (pmt*32 + pl)*68;
  int pcol  = pnt*32 + pl;
  float psc = sc3v[pcol], psh = sh3v[pcol];
  int prbase = 4*(lane>>5);
  FragQ bfr[4];
  #pragma unroll
  for (int kq=0;kq<4;++kq)
    bfr[kq].q = *(const uint4*)&W3T[(size_t)pcol*64 + kq*16 + ko];
  int gmt = w>>1, gnt0 = (w&1)*2, gnt1 = gnt0+1;
  int garow  = (gmt*32 + pl)*68;
  int gbrow0 = (gnt0*32 + pl)*68;
  int gbrow1 = (gnt1*32 + pl)*68;
  floatx16 acc0, acc1;
  #pragma unroll
  for (int q=0;q<16;++q){ acc0[q]=0.f; acc1[q]=0.f; }
  float cs = 0.f;
  int rpc = Mrows / gridDim.x;
  int r0 = blockIdx.x * rpc;
  uint4 hreg = *(const uint4*)&H2[(size_t)(r0+trow)*64 + tc0];
  for (int rb=r0; rb<r0+rpc; rb+=64){
    {
      short* dst = &h2s[trow*68 + tc0];
      *(uint2*)dst       = make_uint2(hreg.x, hreg.y);
      *(uint2*)(dst + 4) = make_uint2(hreg.z, hreg.w);
    }
    if (rb + 64 < r0 + rpc)
      hreg = *(const uint4*)&H2[(size_t)(rb+64+trow)*64 + tc0];
    __syncthreads();
    {
      floatx16 pacc;
      #pragma unroll
      for (int q=0;q<16;++q) pacc[q]=0.f;
      #pragma unroll
      for (int kq=0;kq<4;++kq){
        Frag a;
        const short* ap = &h2s[parow + kq*16 + ko];
        a.u2[0] = *(const uint2*)ap;  a.u2[1] = *(const uint2*)(ap+4);
        pacc = __builtin_amdgcn_mfma_f32_32x32x16_bf16(a.v, bfr[kq].v, pacc, 0, 0, 0);
      }
      #pragma unroll
      for (int g=0; g<4; ++g){
        unsigned short p[4];
        #pragma unroll
        for (int r=0;r<4;++r){
          float v = fmaxf(fmaf(pacc[g*4+r], psc, psh), 0.f);
          cs += v;
          p[r] = f2bu(v);
        }
        uint2 pk; pk.x = p[0] | ((unsigned)p[1]<<16); pk.y = p[2] | ((unsigned)p[3]<<16);
        *(uint2*)&H3T[pcol*68 + pmt*32 + 8*g + prbase] = pk;
      }
    }
    __syncthreads();
    #pragma unroll
    for (int kc=0;kc<64;kc+=16){
      Frag a, b0, b1;
      const short* ap  = &H3T[garow  + kc + ko];
      const short* bp0 = &H3T[gbrow0 + kc + ko];
      const short* bp1 = &H3T[gbrow1 + kc + ko];
      a.u2[0]  = *(const uint2*)ap;   a.u2[1]  = *(const uint2*)(ap+4);
      b0.u2[0] = *(const uint2*)bp0;  b0.u2[1] = *(const uint2*)(bp0+4);
      b1.u2[0] = *(const uint2*)bp1;  b1.u2[1] = *(const uint2*)(bp1+4);
      acc0 = __builtin_amdgcn_mfma_f32_32x32x16_bf16(a.v, b0.v, acc0, 0, 0, 0);
      acc1 = __builtin_amdgcn_mfma_f32_32x32x16_bf16(a.v, b1.v, acc1, 0, 0, 0);
    }
  }
  int col = pl;
  #pragma unroll
  for (int r=0;r<16;++r){
    int row = (r&3) + 8*(r>>2) + prbase;
    atomicAdd(&G4[(size_t)(gmt*32+row)*128 + gnt0*32+col], acc0[r]);
    atomicAdd(&G4[(size_t)(gmt*32+row)*128 + gnt1*32+col], acc1[r]);
  }
  atomicAdd(&csum[pcol], cs);
  __syncthreads();
  if (tid < 128) atomicAdd(&sum4[tid], csum[tid]);
}

// ---------------- fused layers 3+4: MFMA produce chain + col-owner maxpool ----------------
__global__ __launch_bounds__(512,4) void fl34_kernel(const bf16* __restrict__ H2,
    const bf16* __restrict__ W3T, const float* __restrict__ sc3v, const float* __restrict__ sh3v,
    const bf16* __restrict__ W4T, const float* __restrict__ sc4v, const float* __restrict__ sh4v,
    bf16* __restrict__ cat){
  __shared__ short h2s[64*68];             // 8.5 KB
  __shared__ short h3s[64*132];            // 16.5 KB
  __shared__ unsigned short h4s[64*256];   // 32 KB
  __shared__ unsigned short mx3u[16*128];  // 4 KB
  __shared__ unsigned short mx4u[16*256];  // 8 KB
  int tid = threadIdx.x, lane = tid & 63, w = tid >> 6;
  int pl = lane & 31;
  int ko = (lane >> 5)*8;
  int rbase = 4*(lane>>5);
  {
    unsigned* p4 = (unsigned*)mx4u;
    for (int u=tid; u<2048; u+=512) p4[u]=0u;
    unsigned* p3 = (unsigned*)mx3u;
    for (int u=tid; u<1024; u+=512) p3[u]=0u;
  }
  int mt3 = w >> 2, ct3 = w & 3;
  int c3 = ct3*32 + pl;
  float sc3 = sc3v[c3], sh3 = sh3v[c3];
  int a3row = (mt3*32 + pl)*68;
  int c4 = w*32 + pl;
  float sc4 = sc4v[c4], sh4 = sh4v[c4];
  int trow = tid >> 3, tc0 = (tid & 7)*8;
  int r0 = blockIdx.x * 320;
  uint4 hreg = *(const uint4*)&H2[(size_t)(r0+trow)*64 + tc0];
  {
    short* dst = &h2s[trow*68 + tc0];
    *(uint2*)dst       = make_uint2(hreg.x, hreg.y);
    *(uint2*)(dst + 4) = make_uint2(hreg.z, hreg.w);
  }
  hreg = *(const uint4*)&H2[(size_t)(r0 + 64 + trow)*64 + tc0];
  __syncthreads();
  for (int t=0; t<5; ++t){
    {
      floatx16 pa;
      #pragma unroll
      for (int q=0;q<16;++q) pa[q]=0.f;
      #pragma unroll
      for (int kq=0;kq<4;++kq){
        Frag a; FragQ b;
        const short* ap = &h2s[a3row + kq*16 + ko];
        a.u2[0] = *(const uint2*)ap;  a.u2[1] = *(const uint2*)(ap+4);
        b.q = *(const uint4*)&W3T[(size_t)c3*64 + kq*16 + ko];
        pa = __builtin_amdgcn_mfma_f32_32x32x16_bf16(a.v, b.v, pa, 0, 0, 0);
      }
      #pragma unroll
      for (int r=0;r<16;++r){
        int m = mt3*32 + (r&3) + 8*(r>>2) + rbase;
        float v = fmaxf(fmaf(pa[r], sc3, sh3), 0.f);
        h3s[m*132 + c3] = (short)f2bu(v);
      }
    }
    __syncthreads();
    #pragma unroll
    for (int mt4=0; mt4<2; ++mt4){
      floatx16 acc;
      #pragma unroll
      for (int q=0;q<16;++q) acc[q]=0.f;
      int a4row = (mt4*32 + pl)*132;
      #pragma unroll
      for (int kq=0;kq<8;++kq){
        Frag a; FragQ b;
        const short* ap = &h3s[a4row + kq*16 + ko];
        a.u2[0] = *(const uint2*)ap;  a.u2[1] = *(const uint2*)(ap+4);
        b.q = *(const uint4*)&W4T[(size_t)c4*128 + kq*16 + ko];
        acc = __builtin_amdgcn_mfma_f32_32x32x16_bf16(a.v, b.v, acc, 0, 0, 0);
      }
      #pragma unroll
      for (int r=0;r<16;++r){
        int m = mt4*32 + (r&3) + 8*(r>>2) + rbase;
        float v = fmaxf(fmaf(acc[r], sc4, sh4), 0.f);
        h4s[m*256 + c4] = f2bu(v);
      }
    }
    __syncthreads();
    if (t < 4){
      short* dst = &h2s[trow*68 + tc0];
      *(uint2*)dst       = make_uint2(hreg.x, hreg.y);
      *(uint2*)(dst + 4) = make_uint2(hreg.z, hreg.w);
      if (t < 3) hreg = *(const uint4*)&H2[(size_t)(r0 + (t+2)*64 + trow)*64 + tc0];
    }
    {
      int lr0 = t*64;
      if (tid < 256){
        int c = tid;
        int p = lr0/20;
        int nb = (p+1)*20 - lr0;
        unsigned ml = 0;
        for (int r=0;r<64;++r){
          unsigned v = h4s[r*256 + c];
          ml = v > ml ? v : ml;
          if (--nb == 0){
            unsigned short* mp = &mx4u[p*256 + c];
            unsigned cur = *mp;
            if (ml > cur) *mp = (unsigned short)ml;
            ml = 0; ++p; nb = 20;
          }
        }
        if (nb != 20){
          unsigned short* mp = &mx4u[p*256 + c];
          unsigned cur = *mp;
          if (ml > cur) *mp = (unsigned short)ml;
        }
      } else if (tid < 384){
        int c = tid - 256;
        int p = lr0/20;
        int nb = (p+1)*20 - lr0;
        unsigned ml = 0;
        for (int r=0;r<64;++r){
          unsigned v = (unsigned)(unsigned short)h3s[r*132 + c];
          ml = v > ml ? v : ml;
          if (--nb == 0){
            unsigned short* mp = &mx3u[p*128 + c];
            unsigned cur = *mp;
            if (ml > cur) *mp = (unsigned short)ml;
            ml = 0; ++p; nb = 20;
          }
        }
        if (nb != 20){
          unsigned short* mp = &mx3u[p*128 + c];
          unsigned cur = *mp;
          if (ml > cur) *mp = (unsigned short)ml;
        }
      }
    }
    __syncthreads();
  }
  int bn0 = blockIdx.x*16;
  {
    int p = tid >> 5, c0 = (tid & 31)*8;
    uint4 v = *(const uint4*)&mx4u[p*256 + c0];
    *(uint4*)&cat[(size_t)(bn0+p)*512 + 256 + c0] = v;
  }
  if (tid < 256){
    int p = tid >> 4, c0 = (tid & 15)*8;
    uint4 v = *(const uint4*)&mx3u[p*128 + c0];
    *(uint4*)&cat[(size_t)(bn0+p)*512 + 128 + c0] = v;
  }
}

// ---------------- layer 5 v4: double-buffered A-tiles + ob union ----------------
__global__ __launch_bounds__(512) void l5_kernel(const bf16* __restrict__ cat,
                                                const bf16* __restrict__ W5T,
                                                const float* __restrict__ scale,
                                                const float* __restrict__ shift,
                                                float* __restrict__ out){
  __shared__ float obu[64*129];            // 33024 B; aliased as cs2[2][64*68] (17408 B)
  short* cs2 = (short*)obu;
  float* ob = obu;
  int tid = threadIdx.x, lane = tid & 63, w = tid >> 6;
  int pl = lane & 31;
  int ko = (lane >> 5)*8;
  int rbase = 4*(lane>>5);
  int mt = w & 1, ntb = w >> 1;          // nt = ntb + 4*s, s=0..3
  int arow = (mt*32 + pl)*68;
  int trow = tid >> 3, tc0 = (tid & 7)*8;
  int r0 = blockIdx.x*64;
  floatx16 acc[4];
  #pragma unroll
  for (int s=0;s<4;++s)
    #pragma unroll
    for (int q=0;q<16;++q) acc[s][q]=0.f;
  const bf16* arow_g = cat + (size_t)(r0+trow)*512 + tc0;
  uint4 hreg = *(const uint4*)arow_g;
  {
    short* dst = &cs2[trow*68 + tc0];
    *(uint2*)dst       = make_uint2(hreg.x, hreg.y);
    *(uint2*)(dst + 4) = make_uint2(hreg.z, hreg.w);
  }
  hreg = *(const uint4*)(arow_g + 64);
  __syncthreads();
  for (int kc8=0; kc8<8; ++kc8){
    int cur = kc8 & 1;
    if (kc8 < 7){
      short* dst = &cs2[(cur^1)*64*68 + trow*68 + tc0];
      *(uint2*)dst       = make_uint2(hreg.x, hreg.y);
      *(uint2*)(dst + 4) = make_uint2(hreg.z, hreg.w);
      if (kc8 < 6) hreg = *(const uint4*)(arow_g + (kc8+2)*64);
    }
    const short* csb = cs2 + cur*64*68;
    #pragma unroll
    for (int kq=0;kq<4;++kq){
      Frag a;
      const short* ap = &csb[arow + kq*16 + ko];
      a.u2[0] = *(const uint2*)ap;  a.u2[1] = *(const uint2*)(ap+4);
      #pragma unroll
      for (int s=0;s<4;++s){
        FragQ b;
        int col = (ntb + 4*s)*32 + pl;
        b.q = *(const uint4*)&W5T[(size_t)col*512 + kc8*64 + kq*16 + ko];
        acc[s] = __builtin_amdgcn_mfma_f32_32x32x16_bf16(a.v, b.v, acc[s], 0, 0, 0);
      }
    }
    __syncthreads();
  }
  int b = r0 >> 12, n0 = r0 & 4095;
  int colL = ntb*32 + pl;                // 0..127 within chunk
  int colc = tid >> 2, sub = tid & 3;    // writer mapping: 4 threads per col
  for (int s=0;s<4;++s){
    float sc = scale[128*s + colL], sh = shift[128*s + colL];
    #pragma unroll
    for (int q=0;q<16;++q){
      int m = mt*32 + (q&3) + 8*(q>>2) + rbase;
      ob[m*129 + colL] = fmaxf(fmaf(acc[s][q], sc, sh), 0.f);
    }
    __syncthreads();
    float* op = out + ((size_t)b*512 + 128*s + colc)*4096 + n0 + sub*16;
    #pragma unroll
    for (int j=0;j<4;++j){
      int rr = sub*16 + j*4;
      float4 v = make_float4(ob[(rr+0)*129 + colc], ob[(rr+1)*129 + colc],
                             ob[(rr+2)*129 + colc], ob[(rr+3)*129 + colc]);
      *(float4*)(op + j*4) = v;
    }
    __syncthreads();
  }
}

extern "C" void kernel_launch(void* const* d_in, const int* in_sizes, int n_in,
                              void* d_out, int out_size, void* d_ws, size_t ws_size,
                              hipStream_t stream){
  const float* x   = (const float*)d_in[0];
  const float* W1f = (const float*)d_in[1];
  const float* W2f = (const float*)d_in[2];
  const float* W3f = (const float*)d_in[3];
  const float* W4f = (const float*)d_in[4];
  const float* W5f = (const float*)d_in[5];
  const float* g1=(const float*)d_in[6],  *b1=(const float*)d_in[7];
  const float* g2=(const float*)d_in[8],  *b2=(const float*)d_in[9];
  const float* g3=(const float*)d_in[10], *b3=(const float*)d_in[11];
  const float* g4=(const float*)d_in[12], *b4=(const float*)d_in[13];
  const float* g5=(const float*)d_in[14], *b5=(const float*)d_in[15];
  float* out = (float*)d_out;

  char* w = (char*)d_ws;
  size_t off = 0;
  auto alloc = [&](size_t bytes)->void*{
    void* p = w + off;
    off = (off + bytes + 255) & ~(size_t)255;
    return p;
  };

  int*  idxb = (int*) alloc((size_t)BN*Kk*4);
  bf16* H2   = (bf16*)alloc((size_t)Mrows*64*2);
  bf16* catb = (bf16*)alloc((size_t)BN*512*2);
  bf16* W2T  = (bf16*)alloc((size_t)64*64*2);
  bf16* W3T  = (bf16*)alloc((size_t)128*64*2);
  bf16* W4T  = (bf16*)alloc((size_t)256*128*2);
  bf16* W5T  = (bf16*)alloc((size_t)512*512*2);
  float* pv  = (float*)H2;
  int*   pib = (int*)((char*)H2 + (size_t)BN*8*Kk*4);

  size_t statsStart = off;
  float* partf=(float*)alloc(256*48*4);
  float* Gf=(float*)alloc(36*4);
  float* sumf=(float*)alloc(8*4);
  float* G2=(float*)alloc(4096*4);   float* sum2=(float*)alloc(64*4);
  float* G3=(float*)alloc(4096*4);   float* sum3=(float*)alloc(64*4);
  float* G4=(float*)alloc(16384*4);  float* sum4=(float*)alloc(128*4);
  float* G5=(float*)alloc(262144*4); float* sum5=(float*)alloc(512*4);
  float* P1=(float*)alloc(384*4);
  float* P2=(float*)alloc(4096*4);
  float* P3=(float*)alloc(8192*4);
  float* P4=(float*)alloc(32768*4);
  float* P5=(float*)alloc(262144*4);
  float* sc1=(float*)alloc(64*4);   float* sh1=(float*)alloc(64*4);
  float* sc2=(float*)alloc(64*4);   float* sh2=(float*)alloc(64*4);
  float* sc3=(float*)alloc(128*4);  float* sh3=(float*)alloc(128*4);
  float* sc4=(float*)alloc(256*4);  float* sh4=(float*)alloc(256*4);
  float* sc5=(float*)alloc(512*4);  float* sh5=(float*)alloc(512*4);
  size_t statsEnd = off;

  int statsFloats = (int)((statsEnd - statsStart)/4);
  zero_kernel<<<(statsFloats+255)/256,256,0,stream>>>((float*)(w+statsStart), statsFloats);
  w2t_kernel<<<16,256,0,stream>>>(W2f, W2T);
  w3t_kernel<<<32,256,0,stream>>>(W3f, W3T);
  w4t_kernel<<<128,256,0,stream>>>(W4f, W4T);
  w5t_kernel<<<1024,256,0,stream>>>(W5f, W5T);

  knnA_kernel<<<1024,256,0,stream>>>(x, pv, pib);
  knnB_kernel<<<BN/256,256,0,stream>>>(pv, pib, x, idxb, partf);

  const float invM  = 1.0f/(float)Mrows;
  const float invM5 = 1.0f/(float)BN;

  reducef_kernel<<<1,64,0,stream>>>(partf, Gf, sumf);
  kP_kernel<<<2,256,0,stream>>>(Gf, W1f, P1, 6, 64);
  kFinal_kernel<<<4,256,0,stream>>>(P1, sumf, W1f, g1, b1, sc1, sh1, 6, 64, invM);

  stats2_kernel<<<512,512,0,stream>>>(x, idxb, W1f, sc1, sh1, G2, sum2);
  kP_kernel<<<16,256,0,stream>>>(G2, W2f, P2, 64, 64);
  kFinal_kernel<<<4,256,0,stream>>>(P2, sum2, W2f, g2, b2, sc2, sh2, 64, 64, invM);

  fl12_kernel<<<Mrows/320,512,0,stream>>>(x, idxb, W1f, sc1, sh1, W2T, sc2, sh2, H2, catb);

  gram3_kernel<<<512,256,0,stream>>>(H2, Mrows, G3, sum3);
  kP_kernel<<<32,256,0,stream>>>(G3, W3f, P3, 64, 128);
  kFinal_kernel<<<8,256,0,stream>>>(P3, sum3, W3f, g3, b3, sc3, sh3, 64, 128, invM);

  stats4_kernel<<<512,512,0,stream>>>(H2, W3T, sc3, sh3, G4, sum4);
  kP_kernel<<<128,256,0,stream>>>(G4, W4f, P4, 128, 256);
  kFinal_kernel<<<16,256,0,stream>>>(P4, sum4, W4f, g4, b4, sc4, sh4, 128, 256, invM);

  fl34_kernel<<<Mrows/320,512,0,stream>>>(H2, W3T, sc3, sh3, W4T, sc4, sh4, catb);

  gram5_kernel<<<512,256,0,stream>>>(catb, G5, sum5);
  kP512_kernel<<<128,256,0,stream>>>(G5, W5f, P5);
  kFinal_kernel<<<32,256,0,stream>>>(P5, sum5, W5f, g5, b5, sc5, sh5, 512, 512, invM5);
  l5_kernel<<<BN/64,512,0,stream>>>(catb, W5T, sc5, sh5, out);
}